// Round 12
// baseline (73.678 us; speedup 1.0000x reference)
//
#include <hip/hip_runtime.h>
#include <stdint.h>

// CandidateFinder: binary-quantize (x>0), exact match on two 32-bit dim
// groups (union), gather first <=64 matching key indices per query, pad -1.
//
// R11 -> R12: two-node path is dispatch-wall-bound (~7.8us/node: R6 and R11
// have radically different match kernels, identical 63.2us totals). Only
// lever left: ONE node with small GPU work. Fused family's 25us (R5) is
// explained exactly by redundant raw-key LLC traffic: 256 blocks x 512KB =
// 128MB @ ~5.5TB/s ~= 23us, because same-batch blocks land on different
// XCDs. Fix: XCD-aware swizzle (blockIdx.x % 8 = XCD heuristic) packs each
// batch's 64 blocks onto 2 XCDs -> slab fetched once per XCD from LLC
// (4MB), then 31 co-XCD blocks hit the 4MiB XCD-L2 (~4.3TB/s/XCD ->
// ~3.7us). Pack GROUP shrunk 32->16 (no spill risk, a suspect in R10).
// Swizzle affects locality only — correctness is mapping-independent.
//
// wave=64 lanes <-> 64 dims: __ballot(v>0) IS the row's two 32-bit group
// signatures in canonical bit order. Matches emitted in ascending key order
// via ballot+popcount prefix = reference's sort-then-truncate.

#define LSEQ 2048
#define DDIM 64
#define KMAX 64
#define QPB  32   // queries per block -> 64 blocks/batch, 256 total at B=4
#define NW   16   // waves per block (1024 threads)
#define GROUP 16  // key rows loaded branch-free per wave per pass

__global__ __launch_bounds__(1024) void fused_kernel(
    const float* __restrict__ query, const float* __restrict__ key,
    int* __restrict__ out, int swizzle) {
    __shared__ uint2 ks[LSEQ];          // 16 KB: this batch's key signatures

    const int bpb = LSEQ / QPB;         // 64 blocks per batch
    int b, qblk;
    if (swizzle) {
        // B==4, 256 blocks: XCD x = blk&7 -> batch x>>1; batch g occupies
        // XCDs {2g, 2g+1}, 32 blocks each.
        int x = blockIdx.x & 7, i = blockIdx.x >> 3;
        b    = x >> 1;
        qblk = i * 2 + (x & 1);
    } else {
        b    = blockIdx.x / bpb;
        qblk = blockIdx.x % bpb;
    }
    int lane = threadIdx.x & 63;
    int wave = threadIdx.x >> 6;

    // this wave's 2 query signatures first (HBM latency hides under pack)
    const float* qb = query + ((size_t)b * LSEQ + (size_t)qblk * QPB) * DDIM;
    int q0 = wave * 2;                              // local query idx
    float qv0 = qb[(size_t)q0 * DDIM + lane];
    float qv1 = qb[(size_t)(q0 + 1) * DDIM + lane];
    unsigned long long qm0 = __ballot(qv0 > 0.0f);
    unsigned long long qm1 = __ballot(qv1 > 0.0f);

    // ---- pack all 2048 key rows: 128/wave in 8 branch-free groups of 16 ----
    const float* kb = key + (size_t)b * LSEQ * DDIM;
    for (int g = 0; g < LSEQ / (NW * GROUP); ++g) { // 8 groups
        float v[GROUP];
#pragma unroll
        for (int u = 0; u < GROUP; ++u)             // 16 loads, one BB,
            v[u] = kb[(size_t)(g * (NW * GROUP) + u * NW + wave) * DDIM + lane];
        unsigned long long m[GROUP];
#pragma unroll
        for (int u = 0; u < GROUP; ++u)             // branchless (scalar dst)
            m[u] = __ballot(v[u] > 0.0f);
        if (lane == 0) {                            // ONE exec toggle / group
#pragma unroll
            for (int u = 0; u < GROUP; ++u)
                ks[g * (NW * GROUP) + u * NW + wave] =
                    make_uint2((unsigned)m[u], (unsigned)(m[u] >> 32));
        }
    }
    __syncthreads();

    // ---- scan: 2 queries/wave, 16 uint4 LDS loads each (2 keys/lane) ----
    const uint4* kt4 = (const uint4*)ks;
    unsigned long long below = (1ull << lane) - 1ull;
    for (int t = 0; t < 2; ++t) {
        unsigned long long qm = t ? qm1 : qm0;
        unsigned qa = (unsigned)qm, qg = (unsigned)(qm >> 32);
        int* ob = out + ((size_t)b * LSEQ + (size_t)qblk * QPB + q0 + t) * KMAX;

        // fast path: fully branchless, 16 ds_read_b128 back-to-back
        unsigned long long acc = 0;
        int cnt = 0;
#pragma unroll
        for (int i = 0; i < LSEQ / 128; ++i) {      // 16 iters, 128 keys
            uint4 kv = kt4[i * 64 + lane];
            bool mA = (kv.x == qa) | (kv.y == qg);  // key 2*(i*64+lane)
            bool mB = (kv.z == qa) | (kv.w == qg);  // key 2*(i*64+lane)+1
            unsigned long long s;
            s = __ballot(mA); acc |= s; cnt += __popcll(s);
            s = __ballot(mB); acc |= s; cnt += __popcll(s);
        }

        if (acc != 0) {                             // wave-uniform, p~2^-26:
            // exact ordered emit (ascending key idx = sort-then-truncate)
            int c2 = 0;
            for (int c = 0; c < LSEQ / 64; ++c) {
                uint2 kv = ks[c * 64 + lane];
                bool m = (kv.x == qa) || (kv.y == qg);
                unsigned long long mask = __ballot(m);
                if (m) {
                    int pos = c2 + __popcll(mask & below);
                    if (pos < KMAX) ob[pos] = c * 64 + lane;
                }
                c2 += __popcll(mask);
            }
        }
        // pad remaining slots with -1 (64 lanes == KMAX; disjoint vs matches)
        if (lane >= cnt) ob[lane] = -1;
    }
}

extern "C" void kernel_launch(void* const* d_in, const int* in_sizes, int n_in,
                              void* d_out, int out_size, void* d_ws, size_t ws_size,
                              hipStream_t stream) {
    const float* q = (const float*)d_in[0];
    const float* k = (const float*)d_in[1];
    // d_in[2] = head_idx, unused (inputs are already per-head)
    int* out = (int*)d_out;

    int total = in_sizes[0];             // B * L * D
    int B = total / (LSEQ * DDIM);       // = 4

    int grid = B * (LSEQ / QPB);
    int swizzle = (B == 4 && grid == 256) ? 1 : 0;
    fused_kernel<<<grid, 1024, 0, stream>>>(q, k, out, swizzle);
}